// Round 9
// baseline (443.794 us; speedup 1.0000x reference)
//
#include <hip/hip_runtime.h>
#include <math.h>

#define BB 2
#define TT 1024
#define DD 1536
#define HH 12
#define TQK 768
#define TVv 1536
#define CQKV 3072
#define EPSF 1e-6f
#define GBK 32   // GEMM K-step (double-buffered)

typedef __attribute__((ext_vector_type(8))) short short8v;
typedef __attribute__((ext_vector_type(4))) float f32x4;

__device__ __forceinline__ float siluf(float x) { return x / (1.f + expf(-x)); }

__device__ __forceinline__ ushort f2b(float f) {
  union { float f; uint u; } a; a.f = f;
  uint u = a.u;
  uint r = (u + 0x7fffu + ((u >> 16) & 1u)) >> 16;   // round-to-nearest-even
  return (ushort)r;
}
__device__ __forceinline__ float b2f(ushort h) {
  union { uint u; float f; } a; a.u = (uint)h << 16; return a.f;
}

// async global->LDS. dest = wave-uniform base + lane*size; src is PER-LANE.
__device__ __forceinline__ void gload16(const void* g, void* l) {
  __builtin_amdgcn_global_load_lds(
      (const __attribute__((address_space(1))) void*)g,
      (__attribute__((address_space(3))) void*)l, 16, 0, 0);
}

// DPP add: x += lane-permuted x. Pure VALU (no DS pipe).
template <int CTRL>
__device__ __forceinline__ float dpp_xadd(float x) {
  union { float f; int i; } a, b;
  a.f = x;
  b.i = __builtin_amdgcn_update_dpp(0, a.i, CTRL, 0xF, 0xF, true);
  return x + b.f;
}
__device__ __forceinline__ float red16_dpp(float x) {
  x = dpp_xadd<0xB1>(x);   // xor1
  x = dpp_xadd<0x4E>(x);   // xor2
  x = dpp_xadd<0x141>(x);  // row_half_mirror
  x = dpp_xadd<0x140>(x);  // row_mirror
  return x;
}

// ---------------------------------------------------------------------------
// Split-bf16 MFMA GEMM v2: C = X @ W^T via Xl*Wh + Xh*Wl + Xh*Wh.
// 128x128 tile, BK=32, DOUBLE-BUFFERED LDS (4 matrices x 2 bufs x 8KB = 64KB,
// 2 blocks/CU). 2-phase schedule: stage tile k+1 via global_load_lds while
// computing tile k; one barrier per iteration (T3-lite). Swizzle: physical
// 16B-slot p of row r holds logical chunk p ^ ((r>>1)&3) -> frag ds_read_b128
// is 2-way (free); achieved by pre-swizzling the global source per lane.
// ---------------------------------------------------------------------------
__global__ __launch_bounds__(256) void gemm_bf16s(
    const ushort* __restrict__ Xh, const ushort* __restrict__ Xl,
    const ushort* __restrict__ Wh, const ushort* __restrict__ Wl,
    float* __restrict__ C, int M, int N, int K, int ldc)
{
  __shared__ ushort Ah[2][128 * GBK];
  __shared__ ushort Al[2][128 * GBK];
  __shared__ ushort Bh[2][128 * GBK];
  __shared__ ushort Bl[2][128 * GBK];
  const int tid  = threadIdx.x;
  const int lane = tid & 63;
  const int w    = tid >> 6;
  const int wr   = w >> 1, wc = w & 1;
  const int r0   = blockIdx.y * 128, c0 = blockIdx.x * 128;

  const int srow = lane >> 2;   // 0..15 within a 16-row staging group
  const int p    = lane & 3;    // physical 16B slot within row
  const int kcl  = lane >> 4;   // logical K-chunk for fragment reads

  f32x4 acc[4][4];
#pragma unroll
  for (int m = 0; m < 4; ++m)
#pragma unroll
    for (int n = 0; n < 4; ++n)
#pragma unroll
      for (int j = 0; j < 4; ++j) acc[m][n][j] = 0.f;

#define GSTAGE(BUF, K0) do { \
    _Pragma("unroll") \
    for (int j = 0; j < 2; ++j) { \
      const int rb = (w * 2 + j) * 16; \
      const int r  = rb + srow; \
      const int clog = p ^ ((r >> 1) & 3); \
      const size_t xo = (size_t)(r0 + r) * K + (K0) + clog * 8; \
      const size_t wo = (size_t)(c0 + r) * K + (K0) + clog * 8; \
      gload16(Xh + xo, &Ah[BUF][rb * GBK]); \
      gload16(Xl + xo, &Al[BUF][rb * GBK]); \
      gload16(Wh + wo, &Bh[BUF][rb * GBK]); \
      gload16(Wl + wo, &Bl[BUF][rb * GBK]); \
    } \
  } while (0)

#define GCOMP(BUF) do { \
    short8v ah[4], al_[4], bh[4], bl[4]; \
    _Pragma("unroll") \
    for (int m = 0; m < 4; ++m) { \
      const int ra = wr * 64 + m * 16 + (lane & 15); \
      const int ao = ra * GBK + ((kcl ^ ((ra >> 1) & 3)) << 3); \
      ah[m]  = *(const short8v*)(&Ah[BUF][ao]); \
      al_[m] = *(const short8v*)(&Al[BUF][ao]); \
    } \
    _Pragma("unroll") \
    for (int n = 0; n < 4; ++n) { \
      const int rbx = wc * 64 + n * 16 + (lane & 15); \
      const int bo  = rbx * GBK + ((kcl ^ ((rbx >> 1) & 3)) << 3); \
      bh[n] = *(const short8v*)(&Bh[BUF][bo]); \
      bl[n] = *(const short8v*)(&Bl[BUF][bo]); \
    } \
    _Pragma("unroll") \
    for (int m = 0; m < 4; ++m) \
      _Pragma("unroll") \
      for (int n = 0; n < 4; ++n) { \
        acc[m][n] = __builtin_amdgcn_mfma_f32_16x16x32_bf16(al_[m], bh[n], acc[m][n], 0, 0, 0); \
        acc[m][n] = __builtin_amdgcn_mfma_f32_16x16x32_bf16(ah[m], bl[n], acc[m][n], 0, 0, 0); \
        acc[m][n] = __builtin_amdgcn_mfma_f32_16x16x32_bf16(ah[m], bh[n], acc[m][n], 0, 0, 0); \
      } \
  } while (0)

  GSTAGE(0, 0);
  asm volatile("s_waitcnt vmcnt(0)" ::: "memory");
  __syncthreads();

  int buf = 0;
  const int nks = K / GBK;
  for (int ks = 0; ks < nks; ++ks) {
    if (ks + 1 < nks) GSTAGE(buf ^ 1, (ks + 1) * GBK);   // loads fly over compute
    GCOMP(buf);
    __syncthreads();   // compiler-inserted vmcnt/lgkm drain: loads had whole MFMA phase
    buf ^= 1;
  }
#undef GSTAGE
#undef GCOMP

  const int crow = (lane >> 4) * 4;
  const int ccol = lane & 15;
#pragma unroll
  for (int m = 0; m < 4; ++m)
#pragma unroll
    for (int j = 0; j < 4; ++j) {
      float* cp = C + (size_t)(r0 + wr * 64 + m * 16 + crow + j) * ldc + c0 + wc * 64 + ccol;
#pragma unroll
      for (int n = 0; n < 4; ++n) cp[n * 16] = acc[m][n][j];
    }
}

// ---------------------------------------------------------------------------
// f32 -> (bf16 hi, bf16 lo) split casts.
// ---------------------------------------------------------------------------
__device__ __forceinline__ void split8_store(const float* f, ushort* hi, ushort* lo, size_t e)
{
  ushort h[8], l[8];
#pragma unroll
  for (int j = 0; j < 8; ++j) {
    h[j] = f2b(f[j]);
    l[j] = f2b(f[j] - b2f(h[j]));
  }
  uint4 ph, pl;
  ph.x = (uint)h[0] | ((uint)h[1] << 16); ph.y = (uint)h[2] | ((uint)h[3] << 16);
  ph.z = (uint)h[4] | ((uint)h[5] << 16); ph.w = (uint)h[6] | ((uint)h[7] << 16);
  pl.x = (uint)l[0] | ((uint)l[1] << 16); pl.y = (uint)l[2] | ((uint)l[3] << 16);
  pl.z = (uint)l[4] | ((uint)l[5] << 16); pl.w = (uint)l[6] | ((uint)l[7] << 16);
  *(uint4*)(hi + e) = ph;
  *(uint4*)(lo + e) = pl;
}

__global__ void cast_pair_kernel(const float* __restrict__ src,
                                 ushort* __restrict__ hi, ushort* __restrict__ lo)
{
  int cid = blockIdx.x * blockDim.x + threadIdx.x;
  size_t e = (size_t)cid * 8;
  float f[8];
  *(float4*)(f)     = *(const float4*)(src + e);
  *(float4*)(f + 4) = *(const float4*)(src + e + 4);
  split8_store(f, hi, lo, e);
}

__global__ void cast_qkv_kernel(const float* __restrict__ wq, const float* __restrict__ wk,
                                const float* __restrict__ wv,
                                ushort* __restrict__ hi, ushort* __restrict__ lo)
{
  int cid = blockIdx.x * blockDim.x + threadIdx.x;
  size_t e = (size_t)cid * 8;
  const float* src; size_t off;
  if (e < 1179648)      { src = wq; off = e; }
  else if (e < 2359296) { src = wk; off = e - 1179648; }
  else                  { src = wv; off = e - 2359296; }
  float f[8];
  *(float4*)(f)     = *(const float4*)(src + off);
  *(float4*)(f + 4) = *(const float4*)(src + off + 4);
  split8_store(f, hi, lo, e);
}

// ---------------------------------------------------------------------------
// Causal depthwise conv (K=4) + SiLU; writes q/k/v transposed to (B,H,T,D).
// ---------------------------------------------------------------------------
__global__ void conv_silu_kernel(
    const float* __restrict__ pre,
    const float* __restrict__ qw, const float* __restrict__ kw, const float* __restrict__ vw,
    float* __restrict__ qc, float* __restrict__ kc, float* __restrict__ vc)
{
  int idx = blockIdx.x * blockDim.x + threadIdx.x;
  if (idx >= BB * TT * CQKV) return;
  int c  = idx % CQKV;
  int bt = idx / CQKV;
  int t  = bt % TT;
  int b  = bt / TT;

  const float* wp;
  if (c < TQK)          wp = qw + (size_t)c * 4;
  else if (c < 2 * TQK) wp = kw + (size_t)(c - TQK) * 4;
  else                  wp = vw + (size_t)(c - 2 * TQK) * 4;

  float s = 0.f;
#pragma unroll
  for (int j = 0; j < 4; ++j) {
    int ts = t - 3 + j;
    if (ts >= 0) s = fmaf(pre[(size_t)(b * TT + ts) * CQKV + c], wp[j], s);
  }
  s = siluf(s);

  if (c < TQK) {
    int h = c >> 6, d = c & 63;
    qc[((size_t)(b * HH + h) * TT + t) * 64 + d] = s;
  } else if (c < 2 * TQK) {
    int c2 = c - TQK; int h = c2 >> 6, d = c2 & 63;
    kc[((size_t)(b * HH + h) * TT + t) * 64 + d] = s;
  } else {
    int c2 = c - 2 * TQK; int h = c2 >> 7, d = c2 & 127;
    vc[((size_t)(b * HH + h) * TT + t) * 128 + d] = s;
  }
}

__global__ void l2norm64_kernel(float* __restrict__ buf, int nrows)
{
  int gid  = blockIdx.x * blockDim.x + threadIdx.x;
  int row  = gid >> 6;
  int lane = threadIdx.x & 63;
  if (row >= nrows) return;
  float v = buf[(size_t)row * 64 + lane];
  float ss = v * v;
#pragma unroll
  for (int m = 32; m >= 1; m >>= 1) ss += __shfl_xor(ss, m, 64);
  float n = sqrtf(ss);
  buf[(size_t)row * 64 + lane] = v / fmaxf(n, EPSF);
}

// ---------------------------------------------------------------------------
// Gating: one block per row m; 4 waves x 6 outputs. Writes INTERLEAVED
// (alpha,beta) pairs: abi[((b*HH+h)*TT + t)*2 + {0,1}].
// ---------------------------------------------------------------------------
__global__ __launch_bounds__(256) void gate_kernel(
    const float* __restrict__ x, const float* __restrict__ w_a, const float* __restrict__ w_b,
    const float* __restrict__ A_log, const float* __restrict__ dt_bias,
    float* __restrict__ abi)
{
  const int m    = blockIdx.x;
  const int w    = threadIdx.x >> 6;
  const int lane = threadIdx.x & 63;
  const float* xr = x + (size_t)m * DD;
  float xv[24];
#pragma unroll
  for (int i = 0; i < 24; ++i) xv[i] = xr[lane + i * 64];
  const int b = m / TT, t = m % TT;
#pragma unroll
  for (int j = 0; j < 6; ++j) {
    int o = w * 6 + j;
    bool isA = o < HH;
    int h = isA ? o : o - HH;
    const float* wr = (isA ? w_a : w_b) + (size_t)h * DD;
    float s = 0.f;
#pragma unroll
    for (int i = 0; i < 24; ++i) s = fmaf(xv[i], wr[lane + i * 64], s);
#pragma unroll
    for (int mm = 32; mm >= 1; mm >>= 1) s += __shfl_xor(s, mm, 64);
    if (lane == 0) {
      size_t idx = ((size_t)(b * HH + h) * TT + t) * 2;
      if (isA) {
        float a  = s + dt_bias[h];
        float sp = (a > 20.f) ? a : log1pf(expf(a));
        abi[idx] = expf(-expf(A_log[h]) * sp);
      } else {
        abi[idx + 1] = 2.f / (1.f + expf(-s));
      }
    }
  }
}

// ---------------------------------------------------------------------------
// Gated delta scan v5: register-resident (R8 structure) with the software
// pipeline PINNED via sched_barrier(0) at every load/compute seam so the
// compiler cannot collapse the A/B double buffer (R8 failure: VGPR=88 ->
// loads sunk to uses -> full latency per chunk). Loads for chunk n+1 issue
// before compute of chunk n; in-order vmem completion means compute's
// auto-waitcnts leave the next chunk's loads in flight.
// 768 blocks = 32 vgroups x 24 bh, one wave each; blk = vg*24 + bh keeps all
// same-bh blocks on XCD bh%8 (R7-proven L2 dedupe of broadcast k/q reads).
// ---------------------------------------------------------------------------
__global__ __launch_bounds__(64) void scan_kernel(
    const float* __restrict__ qc, const float* __restrict__ kc, const float* __restrict__ vc,
    const float* __restrict__ abi, float* __restrict__ o)
{
  const int blk  = blockIdx.x;
  const int bh   = blk % 24;          // XCD affinity: bh%8
  const int vg   = blk / 24;          // 0..31
  const int b    = bh / HH, h = bh % HH;
  const int lane = threadIdx.x;       // 0..63
  const int cp   = lane >> 4;         // 0..3
  const int s    = lane & 15;         // 0..15, owns d = s*4..s*4+3

  const float* kg  = kc + (size_t)bh * TT * 64 + s * 4;
  const float* qg  = qc + (size_t)bh * TT * 64 + s * 4;
  const float* vgp = vc + (size_t)bh * TT * 128 + vg * 4 + cp;
  const float* abp = abi + (size_t)bh * TT * 2;

  float* op = o + ((size_t)b * TT * HH + h) * 128 + vg * 4 + cp;

  float S[4];
#pragma unroll
  for (int i = 0; i < 4; ++i) S[i] = 0.f;

  float4 kA[8], qA[8]; float vA[8]; float2 abA[8];
  float4 kB[8], qB[8]; float vB[8]; float2 abB[8];

#define LOADC(K, Q, V, AB, T0) do { \
    _Pragma("unroll") \
    for (int j = 0; j < 8; ++j) { \
      K[j]  = *(const float4*)(kg + (size_t)((T0) + j) * 64); \
      Q[j]  = *(const float4*)(qg + (size_t)((T0) + j) * 64); \
      V[j]  = vgp[(size_t)((T0) + j) * 128]; \
      AB[j] = *(const float2*)(abp + ((T0) + j) * 2); \
    } \
  } while (0)

#define STEPS(K, Q, V, AB) do { \
    _Pragma("unroll") \
    for (int j = 0; j < 8; ++j) { \
      const float4 kk = K[j]; const float4 qq = Q[j]; \
      const float vt = V[j]; \
      const float al = AB[j].x, be = AB[j].y; \
      float pa = fmaf(kk.y, S[1], kk.x * S[0]); \
      float pb = fmaf(kk.w, S[3], kk.z * S[2]); \
      float sa = fmaf(qq.y, S[1], qq.x * S[0]); \
      float sb = fmaf(qq.w, S[3], qq.z * S[2]); \
      float ta = fmaf(qq.y, kk.y, qq.x * kk.x); \
      float tb = fmaf(qq.w, kk.w, qq.z * kk.z); \
      float part = red16_dpp(pa + pb); \
      float qs   = red16_dpp(sa + sb); \
      float qk   = red16_dpp(ta + tb); \
      const float c = fmaf(-al * be, part, vt); \
      S[0] = fmaf(al, S[0], c * kk.x); \
      S[1] = fmaf(al, S[1], c * kk.y); \
      S[2] = fmaf(al, S[2], c * kk.z); \
      S[3] = fmaf(al, S[3], c * kk.w); \
      if (s == 0) *op = fmaf(al, qs, c * qk); \
      op += HH * 128; \
    } \
  } while (0)

  LOADC(kA, qA, vA, abA, 0);
  for (int t0 = 0; t0 < TT; t0 += 16) {
    LOADC(kB, qB, vB, abB, t0 + 8);          // issue B while computing A
    __builtin_amdgcn_sched_barrier(0);
    STEPS(kA, qA, vA, abA);
    __builtin_amdgcn_sched_barrier(0);
    if (t0 + 16 < TT) LOADC(kA, qA, vA, abA, t0 + 16);   // issue A' while computing B
    __builtin_amdgcn_sched_barrier(0);
    STEPS(kB, qB, vB, abB);
    __builtin_amdgcn_sched_barrier(0);
  }
#undef LOADC
#undef STEPS
}

// ---------------------------------------------------------------------------
// RMS norm over 128 + SiLU gate; emits split bf16 (hi+lo) for final GEMM.
// ---------------------------------------------------------------------------
__global__ void rmsgate_kernel(const float* __restrict__ o, const float* __restrict__ gpre,
                               ushort* __restrict__ goh, ushort* __restrict__ gol)
{
  int gid  = blockIdx.x * blockDim.x + threadIdx.x;
  int wid  = gid >> 6;
  int lane = threadIdx.x & 63;
  if (wid >= BB * TT * HH) return;
  int h = wid % HH;
  int m = wid / HH;
  const float* orow = o + (size_t)wid * 128;
  float2 ov = *(const float2*)(orow + lane * 2);
  float ss = ov.x * ov.x + ov.y * ov.y;
#pragma unroll
  for (int mm = 32; mm >= 1; mm >>= 1) ss += __shfl_xor(ss, mm, 64);
  float scale = rsqrtf(ss * (1.f / 128.f) + EPSF);
  const float* gr = gpre + (size_t)m * TVv + h * 128 + lane * 2;
  float o0 = ov.x * scale * siluf(gr[0]);
  float o1 = ov.y * scale * siluf(gr[1]);
  ushort h0 = f2b(o0), h1 = f2b(o1);
  ushort l0 = f2b(o0 - b2f(h0)), l1 = f2b(o1 - b2f(h1));
  size_t idx = (size_t)m * TVv + h * 128 + lane * 2;
  *(uint*)(goh + idx) = (uint)h0 | ((uint)h1 << 16);
  *(uint*)(gol + idx) = (uint)l0 | ((uint)l1 << 16);
}

// ---------------------------------------------------------------------------
extern "C" void kernel_launch(void* const* d_in, const int* in_sizes, int n_in,
                              void* d_out, int out_size, void* d_ws, size_t ws_size,
                              hipStream_t stream) {
  (void)in_sizes; (void)n_in; (void)out_size; (void)ws_size;
  const float* x       = (const float*)d_in[0];
  const float* w_q     = (const float*)d_in[1];
  const float* w_k     = (const float*)d_in[2];
  const float* w_v     = (const float*)d_in[3];
  const float* w_a     = (const float*)d_in[4];
  const float* w_b     = (const float*)d_in[5];
  const float* w_g     = (const float*)d_in[6];
  const float* w_out   = (const float*)d_in[7];
  const float* A_log   = (const float*)d_in[8];
  const float* dt_bias = (const float*)d_in[9];
  const float* qcw     = (const float*)d_in[10];
  const float* kcw     = (const float*)d_in[11];
  const float* vcw     = (const float*)d_in[12];

  // Workspace (63.11 MB, same proven footprint).
  float* ws      = (float*)d_ws;
  float* qkv_pre = ws;
  float* g_pre   = ws + 6291456;
  float* Cu      = ws + 9437184;
  float* abi     = ws + 15728640;   // 49152 floats = 24576 (alpha,beta) pairs

  ushort* xh    = (ushort*)Cu;
  ushort* xl    = (ushort*)(Cu + 1572864);
  ushort* wcath = (ushort*)g_pre;
  ushort* wcatl = (ushort*)(Cu + 3145728);
  ushort* wgh   = (ushort*)(Cu + 3145728);
  ushort* wgl   = (ushort*)(Cu + 4325376);

  float* qc = Cu;
  float* kc = Cu + 1572864;
  float* vc = Cu + 3145728;

  ushort* wouth = (ushort*)Cu;
  ushort* woutl = (ushort*)(Cu + 1179648);

  float*  o   = qkv_pre;
  ushort* goh = (ushort*)(qkv_pre + 3145728);
  ushort* gol = (ushort*)(qkv_pre + 4718592);

  const int M = BB * TT;  // 2048
  dim3 blk(256);

  // 1) split-casts: x, concatenated q|k|v weights
  cast_pair_kernel<<<1536, blk, 0, stream>>>(x, xh, xl);
  cast_qkv_kernel<<<2304, blk, 0, stream>>>(w_q, w_k, w_v, wcath, wcatl);

  // 2) fused qkv projection (N=3072)
  gemm_bf16s<<<dim3(CQKV / 128, M / 128), blk, 0, stream>>>(xh, xl, wcath, wcatl, qkv_pre, M, CQKV, DD, CQKV);

  // 3) g projection
  cast_pair_kernel<<<1152, blk, 0, stream>>>(w_g, wgh, wgl);
  gemm_bf16s<<<dim3(TVv / 128, M / 128), blk, 0, stream>>>(xh, xl, wgh, wgl, g_pre, M, TVv, DD, TVv);

  // 4) gating coefficients -> interleaved (alpha,beta)
  gate_kernel<<<M, blk, 0, stream>>>(x, w_a, w_b, A_log, dt_bias, abi);

  // 5) causal depthwise conv + SiLU
  conv_silu_kernel<<<(BB * TT * CQKV + 255) / 256, blk, 0, stream>>>(qkv_pre, qcw, kcw, vcw, qc, kc, vc);

  // 6) L2 normalize q,k
  l2norm64_kernel<<<6144, blk, 0, stream>>>(qc, BB * HH * TT);
  l2norm64_kernel<<<6144, blk, 0, stream>>>(kc, BB * HH * TT);

  // 7) scan v5: register-resident, pipeline pinned with sched_barrier(0)
  scan_kernel<<<768, dim3(64), 0, stream>>>(qc, kc, vc, abi, o);

  // 8) split-cast w_out
  cast_pair_kernel<<<1152, blk, 0, stream>>>(w_out, wouth, woutl);

  // 9) RMS norm + SiLU gate -> split bf16
  rmsgate_kernel<<<6144, blk, 0, stream>>>(o, g_pre, goh, gol);

  // 10) output projection
  gemm_bf16s<<<dim3(TVv / 128, M / 128), blk, 0, stream>>>(goh, gol, wouth, woutl, (float*)d_out, M, TVv, DD, TVv);
}

// Round 10
// 395.513 us; speedup vs baseline: 1.1221x; 1.1221x over previous
//
#include <hip/hip_runtime.h>
#include <math.h>

#define BB 2
#define TT 1024
#define DD 1536
#define HH 12
#define TQK 768
#define TVv 1536
#define CQKV 3072
#define EPSF 1e-6f
#define TSC 32   // scan time-tile (per LDS buffer)

typedef __attribute__((ext_vector_type(8))) short short8v;
typedef __attribute__((ext_vector_type(4))) float f32x4;

__device__ __forceinline__ float siluf(float x) { return x / (1.f + expf(-x)); }

__device__ __forceinline__ ushort f2b(float f) {
  union { float f; uint u; } a; a.f = f;
  uint u = a.u;
  uint r = (u + 0x7fffu + ((u >> 16) & 1u)) >> 16;   // round-to-nearest-even
  return (ushort)r;
}
__device__ __forceinline__ float b2f(ushort h) {
  union { uint u; float f; } a; a.u = (uint)h << 16; return a.f;
}

// async global->LDS. dest = wave-uniform base + lane*size; src is PER-LANE.
__device__ __forceinline__ void gload16(const void* g, void* l) {
  __builtin_amdgcn_global_load_lds(
      (const __attribute__((address_space(1))) void*)g,
      (__attribute__((address_space(3))) void*)l, 16, 0, 0);
}
__device__ __forceinline__ void gload4(const void* g, void* l) {
  __builtin_amdgcn_global_load_lds(
      (const __attribute__((address_space(1))) void*)g,
      (__attribute__((address_space(3))) void*)l, 4, 0, 0);
}

// DPP add: x += lane-permuted x. Pure VALU (no DS pipe).
template <int CTRL>
__device__ __forceinline__ float dpp_xadd(float x) {
  union { float f; int i; } a, b;
  a.f = x;
  b.i = __builtin_amdgcn_update_dpp(0, a.i, CTRL, 0xF, 0xF, true);
  return x + b.f;
}
__device__ __forceinline__ float red16_dpp(float x) {
  x = dpp_xadd<0xB1>(x);   // xor1
  x = dpp_xadd<0x4E>(x);   // xor2
  x = dpp_xadd<0x141>(x);  // row_half_mirror
  x = dpp_xadd<0x140>(x);  // row_mirror
  return x;
}

// ---------------------------------------------------------------------------
// Split-bf16 MFMA GEMM (R6/R8 version — best measured): C = X @ W^T via
// Xl*Wh + Xh*Wl + Xh*Wh; 128x128 tile, BK=64, single-buffered
// global_load_lds staging with XOR-swizzled source + swizzled ds_read.
// ---------------------------------------------------------------------------
__global__ __launch_bounds__(256) void gemm_bf16s(
    const ushort* __restrict__ Xh, const ushort* __restrict__ Xl,
    const ushort* __restrict__ Wh, const ushort* __restrict__ Wl,
    float* __restrict__ C, int M, int N, int K, int ldc)
{
  __shared__ ushort Ah[128 * 64];
  __shared__ ushort Al[128 * 64];
  __shared__ ushort Bh[128 * 64];
  __shared__ ushort Bl[128 * 64];
  const int tid  = threadIdx.x;
  const int lane = tid & 63;
  const int w    = tid >> 6;
  const int wr   = w >> 1, wc = w & 1;
  const int r0   = blockIdx.y * 128, c0 = blockIdx.x * 128;

  const int dr   = lane >> 3;
  const int slot = (lane & 7) ^ dr;

  f32x4 acc[4][4];
#pragma unroll
  for (int m = 0; m < 4; ++m)
#pragma unroll
    for (int n = 0; n < 4; ++n)
#pragma unroll
      for (int j = 0; j < 4; ++j) acc[m][n][j] = 0.f;

  for (int k0 = 0; k0 < K; k0 += 64) {
#pragma unroll
    for (int j = 0; j < 4; ++j) {
      const int row  = (w * 4 + j) * 8 + dr;
      const size_t xo = (size_t)(r0 + row) * K + k0 + slot * 8;
      const size_t wo = (size_t)(c0 + row) * K + k0 + slot * 8;
      const int ldso = (w * 4 + j) * 512;
      gload16(Xh + xo, Ah + ldso);
      gload16(Xl + xo, Al + ldso);
      gload16(Wh + wo, Bh + ldso);
      gload16(Wl + wo, Bl + ldso);
    }
    __syncthreads();
#pragma unroll
    for (int kk = 0; kk < 2; ++kk) {
      const int kc8 = kk * 4 + (lane >> 4);
      const int sw  = (kc8 ^ (lane & 7)) << 3;
      short8v ah[4], al_[4], bh[4], bl[4];
#pragma unroll
      for (int m = 0; m < 4; ++m) {
        const int ro = (wr * 64 + m * 16 + (lane & 15)) * 64 + sw;
        ah[m]  = *(const short8v*)(Ah + ro);
        al_[m] = *(const short8v*)(Al + ro);
      }
#pragma unroll
      for (int n = 0; n < 4; ++n) {
        const int ro = (wc * 64 + n * 16 + (lane & 15)) * 64 + sw;
        bh[n] = *(const short8v*)(Bh + ro);
        bl[n] = *(const short8v*)(Bl + ro);
      }
#pragma unroll
      for (int m = 0; m < 4; ++m)
#pragma unroll
        for (int n = 0; n < 4; ++n) {
          acc[m][n] = __builtin_amdgcn_mfma_f32_16x16x32_bf16(al_[m], bh[n], acc[m][n], 0, 0, 0);
          acc[m][n] = __builtin_amdgcn_mfma_f32_16x16x32_bf16(ah[m], bl[n], acc[m][n], 0, 0, 0);
          acc[m][n] = __builtin_amdgcn_mfma_f32_16x16x32_bf16(ah[m], bh[n], acc[m][n], 0, 0, 0);
        }
    }
    __syncthreads();
  }

  const int crow = (lane >> 4) * 4;
  const int ccol = lane & 15;
#pragma unroll
  for (int m = 0; m < 4; ++m)
#pragma unroll
    for (int j = 0; j < 4; ++j) {
      float* cp = C + (size_t)(r0 + wr * 64 + m * 16 + crow + j) * ldc + c0 + wc * 64 + ccol;
#pragma unroll
      for (int n = 0; n < 4; ++n) cp[n * 16] = acc[m][n][j];
    }
}

// ---------------------------------------------------------------------------
// f32 -> (bf16 hi, bf16 lo) split casts.
// ---------------------------------------------------------------------------
__device__ __forceinline__ void split8_store(const float* f, ushort* hi, ushort* lo, size_t e)
{
  ushort h[8], l[8];
#pragma unroll
  for (int j = 0; j < 8; ++j) {
    h[j] = f2b(f[j]);
    l[j] = f2b(f[j] - b2f(h[j]));
  }
  uint4 ph, pl;
  ph.x = (uint)h[0] | ((uint)h[1] << 16); ph.y = (uint)h[2] | ((uint)h[3] << 16);
  ph.z = (uint)h[4] | ((uint)h[5] << 16); ph.w = (uint)h[6] | ((uint)h[7] << 16);
  pl.x = (uint)l[0] | ((uint)l[1] << 16); pl.y = (uint)l[2] | ((uint)l[3] << 16);
  pl.z = (uint)l[4] | ((uint)l[5] << 16); pl.w = (uint)l[6] | ((uint)l[7] << 16);
  *(uint4*)(hi + e) = ph;
  *(uint4*)(lo + e) = pl;
}

__global__ void cast_pair_kernel(const float* __restrict__ src,
                                 ushort* __restrict__ hi, ushort* __restrict__ lo)
{
  int cid = blockIdx.x * blockDim.x + threadIdx.x;
  size_t e = (size_t)cid * 8;
  float f[8];
  *(float4*)(f)     = *(const float4*)(src + e);
  *(float4*)(f + 4) = *(const float4*)(src + e + 4);
  split8_store(f, hi, lo, e);
}

__global__ void cast_qkv_kernel(const float* __restrict__ wq, const float* __restrict__ wk,
                                const float* __restrict__ wv,
                                ushort* __restrict__ hi, ushort* __restrict__ lo)
{
  int cid = blockIdx.x * blockDim.x + threadIdx.x;
  size_t e = (size_t)cid * 8;
  const float* src; size_t off;
  if (e < 1179648)      { src = wq; off = e; }
  else if (e < 2359296) { src = wk; off = e - 1179648; }
  else                  { src = wv; off = e - 2359296; }
  float f[8];
  *(float4*)(f)     = *(const float4*)(src + off);
  *(float4*)(f + 4) = *(const float4*)(src + off + 4);
  split8_store(f, hi, lo, e);
}

// ---------------------------------------------------------------------------
// Causal depthwise conv (K=4) + SiLU; writes q/k/v transposed to (B,H,T,D).
// ---------------------------------------------------------------------------
__global__ void conv_silu_kernel(
    const float* __restrict__ pre,
    const float* __restrict__ qw, const float* __restrict__ kw, const float* __restrict__ vw,
    float* __restrict__ qc, float* __restrict__ kc, float* __restrict__ vc)
{
  int idx = blockIdx.x * blockDim.x + threadIdx.x;
  if (idx >= BB * TT * CQKV) return;
  int c  = idx % CQKV;
  int bt = idx / CQKV;
  int t  = bt % TT;
  int b  = bt / TT;

  const float* wp;
  if (c < TQK)          wp = qw + (size_t)c * 4;
  else if (c < 2 * TQK) wp = kw + (size_t)(c - TQK) * 4;
  else                  wp = vw + (size_t)(c - 2 * TQK) * 4;

  float s = 0.f;
#pragma unroll
  for (int j = 0; j < 4; ++j) {
    int ts = t - 3 + j;
    if (ts >= 0) s = fmaf(pre[(size_t)(b * TT + ts) * CQKV + c], wp[j], s);
  }
  s = siluf(s);

  if (c < TQK) {
    int h = c >> 6, d = c & 63;
    qc[((size_t)(b * HH + h) * TT + t) * 64 + d] = s;
  } else if (c < 2 * TQK) {
    int c2 = c - TQK; int h = c2 >> 6, d = c2 & 63;
    kc[((size_t)(b * HH + h) * TT + t) * 64 + d] = s;
  } else {
    int c2 = c - 2 * TQK; int h = c2 >> 7, d = c2 & 127;
    vc[((size_t)(b * HH + h) * TT + t) * 128 + d] = s;
  }
}

__global__ void l2norm64_kernel(float* __restrict__ buf, int nrows)
{
  int gid  = blockIdx.x * blockDim.x + threadIdx.x;
  int row  = gid >> 6;
  int lane = threadIdx.x & 63;
  if (row >= nrows) return;
  float v = buf[(size_t)row * 64 + lane];
  float ss = v * v;
#pragma unroll
  for (int m = 32; m >= 1; m >>= 1) ss += __shfl_xor(ss, m, 64);
  float n = sqrtf(ss);
  buf[(size_t)row * 64 + lane] = v / fmaxf(n, EPSF);
}

// ---------------------------------------------------------------------------
// Gating: one block per row m; 4 waves x 6 outputs. Writes INTERLEAVED
// (alpha,beta) pairs: abi[((b*HH+h)*TT + t)*2 + {0,1}].
// ---------------------------------------------------------------------------
__global__ __launch_bounds__(256) void gate_kernel(
    const float* __restrict__ x, const float* __restrict__ w_a, const float* __restrict__ w_b,
    const float* __restrict__ A_log, const float* __restrict__ dt_bias,
    float* __restrict__ abi)
{
  const int m    = blockIdx.x;
  const int w    = threadIdx.x >> 6;
  const int lane = threadIdx.x & 63;
  const float* xr = x + (size_t)m * DD;
  float xv[24];
#pragma unroll
  for (int i = 0; i < 24; ++i) xv[i] = xr[lane + i * 64];
  const int b = m / TT, t = m % TT;
#pragma unroll
  for (int j = 0; j < 6; ++j) {
    int o = w * 6 + j;
    bool isA = o < HH;
    int h = isA ? o : o - HH;
    const float* wr = (isA ? w_a : w_b) + (size_t)h * DD;
    float s = 0.f;
#pragma unroll
    for (int i = 0; i < 24; ++i) s = fmaf(xv[i], wr[lane + i * 64], s);
#pragma unroll
    for (int mm = 32; mm >= 1; mm >>= 1) s += __shfl_xor(s, mm, 64);
    if (lane == 0) {
      size_t idx = ((size_t)(b * HH + h) * TT + t) * 2;
      if (isA) {
        float a  = s + dt_bias[h];
        float sp = (a > 20.f) ? a : log1pf(expf(a));
        abi[idx] = expf(-expf(A_log[h]) * sp);
      } else {
        abi[idx + 1] = 2.f / (1.f + expf(-s));
      }
    }
  }
}

// ---------------------------------------------------------------------------
// Gated delta scan v6 = R7 (best measured, 171us) + manual depth-1 register
// prefetch in the 32-step inner loop: step i+1's LDS reads issue before
// step i's compute through NAMED rotating scalars (no arrays -> regalloc
// cannot collapse them; R8/R9 failure mode avoided). In-order lgkm
// completion means compute-i waits only on reads issued for step i, which
// had a full step of latency cover.
// 768 blocks = 32 vgroups x 24 bh, one wave each; blk = vg*24 + bh keeps all
// same-bh blocks on XCD bh%8 (R7-proven L2 dedupe: FETCH 12.4 MB).
// ---------------------------------------------------------------------------
__global__ __launch_bounds__(64) void scan_kernel(
    const float* __restrict__ qc, const float* __restrict__ kc, const float* __restrict__ vc,
    const float* __restrict__ abi, float* __restrict__ o)
{
  __shared__ float k_lds[2][TSC * 64];
  __shared__ float q_lds[2][TSC * 64];
  __shared__ float v_lds[2][TSC * 4];
  __shared__ float ab_lds[2][TSC * 2];

  const int blk  = blockIdx.x;
  const int bh   = blk % 24;          // XCD affinity: bh%8
  const int vg   = blk / 24;          // 0..31
  const int b    = bh / HH, h = bh % HH;
  const int lane = threadIdx.x;       // 0..63
  const int cp   = lane >> 4;         // 0..3
  const int s    = lane & 15;         // 0..15, owns d = s*4..s*4+3

  const float* kg = kc + (size_t)bh * TT * 64;
  const float* qg = qc + (size_t)bh * TT * 64;

  // per-lane gather sources
  const float* vsrc  = vc + (size_t)bh * TT * 128 + (size_t)(lane >> 2) * 128 + vg * 4 + (lane & 3);
  const float* absrc = abi + (size_t)bh * TT * 2 + lane;

  float* op = o + ((size_t)b * TT * HH + h) * 128 + vg * 4 + cp;

#define STAGE(B, T0) do { \
    _Pragma("unroll") \
    for (int j = 0; j < 8; ++j) { \
      gload16(kg + (size_t)((T0) + 4 * j) * 64 + lane * 4, &k_lds[B][j * 256]); \
      gload16(qg + (size_t)((T0) + 4 * j) * 64 + lane * 4, &q_lds[B][j * 256]); \
    } \
    gload4(vsrc + (size_t)(T0) * 128,        &v_lds[B][0]);  \
    gload4(vsrc + (size_t)((T0) + 16) * 128, &v_lds[B][64]); \
    gload4(absrc + (T0) * 2, &ab_lds[B][0]); \
  } while (0)

  float S[4];
#pragma unroll
  for (int i = 0; i < 4; ++i) S[i] = 0.f;

  STAGE(0, 0);
  for (int tile = 0; tile < TT / TSC; ++tile) {
    const int cur = tile & 1;
    if (tile + 1 < TT / TSC) {
      STAGE(cur ^ 1, (tile + 1) * TSC);
      asm volatile("s_waitcnt vmcnt(19)" ::: "memory");
    } else {
      asm volatile("s_waitcnt vmcnt(0)" ::: "memory");
    }
    __builtin_amdgcn_sched_barrier(0);

    // preload step 0 of this tile
    float4 kk = *(const float4*)(&k_lds[cur][s * 4]);
    float4 qq = *(const float4*)(&q_lds[cur][s * 4]);
    float  vt = v_lds[cur][cp];
    float2 ab = *(const float2*)(&ab_lds[cur][0]);

#pragma unroll
    for (int i = 0; i < TSC; ++i) {
      // issue step i+1's reads BEFORE step i's compute (latency cover)
      float4 kkn = kk, qqn = qq; float vtn = vt; float2 abn = ab;
      if (i + 1 < TSC) {
        kkn = *(const float4*)(&k_lds[cur][(i + 1) * 64 + s * 4]);
        qqn = *(const float4*)(&q_lds[cur][(i + 1) * 64 + s * 4]);
        vtn = v_lds[cur][(i + 1) * 4 + cp];
        abn = *(const float2*)(&ab_lds[cur][2 * (i + 1)]);
      }

      const float al = ab.x, be = ab.y;
      float pa = fmaf(kk.y, S[1], kk.x * S[0]);
      float pb = fmaf(kk.w, S[3], kk.z * S[2]);
      float sa = fmaf(qq.y, S[1], qq.x * S[0]);
      float sb = fmaf(qq.w, S[3], qq.z * S[2]);
      float ta = fmaf(qq.y, kk.y, qq.x * kk.x);
      float tb = fmaf(qq.w, kk.w, qq.z * kk.z);

      float part = red16_dpp(pa + pb);   // k.S (serial chain, pure VALU)
      float qs   = red16_dpp(sa + sb);   // q.S (off-chain)
      float qk   = red16_dpp(ta + tb);   // q.k (off-chain)
      const float c = fmaf(-al * be, part, vt);
      S[0] = fmaf(al, S[0], c * kk.x);
      S[1] = fmaf(al, S[1], c * kk.y);
      S[2] = fmaf(al, S[2], c * kk.z);
      S[3] = fmaf(al, S[3], c * kk.w);
      if (s == 0) *op = fmaf(al, qs, c * qk);
      op += HH * 128;

      kk = kkn; qq = qqn; vt = vtn; ab = abn;
    }
  }
#undef STAGE
}

// ---------------------------------------------------------------------------
// RMS norm over 128 + SiLU gate; emits split bf16 (hi+lo) for final GEMM.
// ---------------------------------------------------------------------------
__global__ void rmsgate_kernel(const float* __restrict__ o, const float* __restrict__ gpre,
                               ushort* __restrict__ goh, ushort* __restrict__ gol)
{
  int gid  = blockIdx.x * blockDim.x + threadIdx.x;
  int wid  = gid >> 6;
  int lane = threadIdx.x & 63;
  if (wid >= BB * TT * HH) return;
  int h = wid % HH;
  int m = wid / HH;
  const float* orow = o + (size_t)wid * 128;
  float2 ov = *(const float2*)(orow + lane * 2);
  float ss = ov.x * ov.x + ov.y * ov.y;
#pragma unroll
  for (int mm = 32; mm >= 1; mm >>= 1) ss += __shfl_xor(ss, mm, 64);
  float scale = rsqrtf(ss * (1.f / 128.f) + EPSF);
  const float* gr = gpre + (size_t)m * TVv + h * 128 + lane * 2;
  float o0 = ov.x * scale * siluf(gr[0]);
  float o1 = ov.y * scale * siluf(gr[1]);
  ushort h0 = f2b(o0), h1 = f2b(o1);
  ushort l0 = f2b(o0 - b2f(h0)), l1 = f2b(o1 - b2f(h1));
  size_t idx = (size_t)m * TVv + h * 128 + lane * 2;
  *(uint*)(goh + idx) = (uint)h0 | ((uint)h1 << 16);
  *(uint*)(gol + idx) = (uint)l0 | ((uint)l1 << 16);
}

// ---------------------------------------------------------------------------
extern "C" void kernel_launch(void* const* d_in, const int* in_sizes, int n_in,
                              void* d_out, int out_size, void* d_ws, size_t ws_size,
                              hipStream_t stream) {
  (void)in_sizes; (void)n_in; (void)out_size; (void)ws_size;
  const float* x       = (const float*)d_in[0];
  const float* w_q     = (const float*)d_in[1];
  const float* w_k     = (const float*)d_in[2];
  const float* w_v     = (const float*)d_in[3];
  const float* w_a     = (const float*)d_in[4];
  const float* w_b     = (const float*)d_in[5];
  const float* w_g     = (const float*)d_in[6];
  const float* w_out   = (const float*)d_in[7];
  const float* A_log   = (const float*)d_in[8];
  const float* dt_bias = (const float*)d_in[9];
  const float* qcw     = (const float*)d_in[10];
  const float* kcw     = (const float*)d_in[11];
  const float* vcw     = (const float*)d_in[12];

  // Workspace (63.11 MB, same proven footprint).
  float* ws      = (float*)d_ws;
  float* qkv_pre = ws;
  float* g_pre   = ws + 6291456;
  float* Cu      = ws + 9437184;
  float* abi     = ws + 15728640;   // 49152 floats = 24576 (alpha,beta) pairs

  ushort* xh    = (ushort*)Cu;
  ushort* xl    = (ushort*)(Cu + 1572864);
  ushort* wcath = (ushort*)g_pre;
  ushort* wcatl = (ushort*)(Cu + 3145728);
  ushort* wgh   = (ushort*)(Cu + 3145728);
  ushort* wgl   = (ushort*)(Cu + 4325376);

  float* qc = Cu;
  float* kc = Cu + 1572864;
  float* vc = Cu + 3145728;

  ushort* wouth = (ushort*)Cu;
  ushort* woutl = (ushort*)(Cu + 1179648);

  float*  o   = qkv_pre;
  ushort* goh = (ushort*)(qkv_pre + 3145728);
  ushort* gol = (ushort*)(qkv_pre + 4718592);

  const int M = BB * TT;  // 2048
  dim3 blk(256);

  // 1) split-casts: x, concatenated q|k|v weights
  cast_pair_kernel<<<1536, blk, 0, stream>>>(x, xh, xl);
  cast_qkv_kernel<<<2304, blk, 0, stream>>>(w_q, w_k, w_v, wcath, wcatl);

  // 2) fused qkv projection (N=3072)
  gemm_bf16s<<<dim3(CQKV / 128, M / 128), blk, 0, stream>>>(xh, xl, wcath, wcatl, qkv_pre, M, CQKV, DD, CQKV);

  // 3) g projection
  cast_pair_kernel<<<1152, blk, 0, stream>>>(w_g, wgh, wgl);
  gemm_bf16s<<<dim3(TVv / 128, M / 128), blk, 0, stream>>>(xh, xl, wgh, wgl, g_pre, M, TVv, DD, TVv);

  // 4) gating coefficients -> interleaved (alpha,beta)
  gate_kernel<<<M, blk, 0, stream>>>(x, w_a, w_b, A_log, dt_bias, abi);

  // 5) causal depthwise conv + SiLU
  conv_silu_kernel<<<(BB * TT * CQKV + 255) / 256, blk, 0, stream>>>(qkv_pre, qcw, kcw, vcw, qc, kc, vc);

  // 6) L2 normalize q,k
  l2norm64_kernel<<<6144, blk, 0, stream>>>(qc, BB * HH * TT);
  l2norm64_kernel<<<6144, blk, 0, stream>>>(kc, BB * HH * TT);

  // 7) scan v6: R7 structure + manual register prefetch
  scan_kernel<<<768, dim3(64), 0, stream>>>(qc, kc, vc, abi, o);

  // 8) split-cast w_out
  cast_pair_kernel<<<1152, blk, 0, stream>>>(w_out, wouth, woutl);

  // 9) RMS norm + SiLU gate -> split bf16
  rmsgate_kernel<<<6144, blk, 0, stream>>>(o, g_pre, goh, gol);

  // 10) output projection
  gemm_bf16s<<<dim3(TVv / 128, M / 128), blk, 0, stream>>>(goh, gol, wouth, woutl, (float*)d_out, M, TVv, DD, TVv);
}

// Round 11
// 379.581 us; speedup vs baseline: 1.1692x; 1.0420x over previous
//
#include <hip/hip_runtime.h>
#include <math.h>

#define BB 2
#define TT 1024
#define DD 1536
#define HH 12
#define TQK 768
#define TVv 1536
#define CQKV 3072
#define EPSF 1e-6f
#define TSC 32   // scan time-tile (per LDS buffer)

typedef __attribute__((ext_vector_type(8))) short short8v;
typedef __attribute__((ext_vector_type(4))) float f32x4;

__device__ __forceinline__ float siluf(float x) { return x / (1.f + expf(-x)); }

__device__ __forceinline__ ushort f2b(float f) {
  union { float f; uint u; } a; a.f = f;
  uint u = a.u;
  uint r = (u + 0x7fffu + ((u >> 16) & 1u)) >> 16;   // round-to-nearest-even
  return (ushort)r;
}
__device__ __forceinline__ float b2f(ushort h) {
  union { uint u; float f; } a; a.u = (uint)h << 16; return a.f;
}

// async global->LDS. dest = wave-uniform base + lane*size; src is PER-LANE.
__device__ __forceinline__ void gload16(const void* g, void* l) {
  __builtin_amdgcn_global_load_lds(
      (const __attribute__((address_space(1))) void*)g,
      (__attribute__((address_space(3))) void*)l, 16, 0, 0);
}
__device__ __forceinline__ void gload4(const void* g, void* l) {
  __builtin_amdgcn_global_load_lds(
      (const __attribute__((address_space(1))) void*)g,
      (__attribute__((address_space(3))) void*)l, 4, 0, 0);
}

// DPP add: x += lane-permuted x. Pure VALU (no DS pipe).
template <int CTRL>
__device__ __forceinline__ float dpp_xadd(float x) {
  union { float f; int i; } a, b;
  a.f = x;
  b.i = __builtin_amdgcn_update_dpp(0, a.i, CTRL, 0xF, 0xF, true);
  return x + b.f;
}
__device__ __forceinline__ float red16_dpp(float x) {
  x = dpp_xadd<0xB1>(x);   // xor1
  x = dpp_xadd<0x4E>(x);   // xor2
  x = dpp_xadd<0x141>(x);  // row_half_mirror
  x = dpp_xadd<0x140>(x);  // row_mirror
  return x;
}

// ---------------------------------------------------------------------------
// Split-bf16 MFMA GEMM (best measured config): C = X @ W^T via
// Xl*Wh + Xh*Wl + Xh*Wh; 128x128 tile, BK=64, single-buffered
// global_load_lds staging with XOR-swizzled source + swizzled ds_read.
// ---------------------------------------------------------------------------
__global__ __launch_bounds__(256) void gemm_bf16s(
    const ushort* __restrict__ Xh, const ushort* __restrict__ Xl,
    const ushort* __restrict__ Wh, const ushort* __restrict__ Wl,
    float* __restrict__ C, int M, int N, int K, int ldc)
{
  __shared__ ushort Ah[128 * 64];
  __shared__ ushort Al[128 * 64];
  __shared__ ushort Bh[128 * 64];
  __shared__ ushort Bl[128 * 64];
  const int tid  = threadIdx.x;
  const int lane = tid & 63;
  const int w    = tid >> 6;
  const int wr   = w >> 1, wc = w & 1;
  const int r0   = blockIdx.y * 128, c0 = blockIdx.x * 128;

  const int dr   = lane >> 3;
  const int slot = (lane & 7) ^ dr;

  f32x4 acc[4][4];
#pragma unroll
  for (int m = 0; m < 4; ++m)
#pragma unroll
    for (int n = 0; n < 4; ++n)
#pragma unroll
      for (int j = 0; j < 4; ++j) acc[m][n][j] = 0.f;

  for (int k0 = 0; k0 < K; k0 += 64) {
#pragma unroll
    for (int j = 0; j < 4; ++j) {
      const int row  = (w * 4 + j) * 8 + dr;
      const size_t xo = (size_t)(r0 + row) * K + k0 + slot * 8;
      const size_t wo = (size_t)(c0 + row) * K + k0 + slot * 8;
      const int ldso = (w * 4 + j) * 512;
      gload16(Xh + xo, Ah + ldso);
      gload16(Xl + xo, Al + ldso);
      gload16(Wh + wo, Bh + ldso);
      gload16(Wl + wo, Bl + ldso);
    }
    __syncthreads();
#pragma unroll
    for (int kk = 0; kk < 2; ++kk) {
      const int kc8 = kk * 4 + (lane >> 4);
      const int sw  = (kc8 ^ (lane & 7)) << 3;
      short8v ah[4], al_[4], bh[4], bl[4];
#pragma unroll
      for (int m = 0; m < 4; ++m) {
        const int ro = (wr * 64 + m * 16 + (lane & 15)) * 64 + sw;
        ah[m]  = *(const short8v*)(Ah + ro);
        al_[m] = *(const short8v*)(Al + ro);
      }
#pragma unroll
      for (int n = 0; n < 4; ++n) {
        const int ro = (wc * 64 + n * 16 + (lane & 15)) * 64 + sw;
        bh[n] = *(const short8v*)(Bh + ro);
        bl[n] = *(const short8v*)(Bl + ro);
      }
#pragma unroll
      for (int m = 0; m < 4; ++m)
#pragma unroll
        for (int n = 0; n < 4; ++n) {
          acc[m][n] = __builtin_amdgcn_mfma_f32_16x16x32_bf16(al_[m], bh[n], acc[m][n], 0, 0, 0);
          acc[m][n] = __builtin_amdgcn_mfma_f32_16x16x32_bf16(ah[m], bl[n], acc[m][n], 0, 0, 0);
          acc[m][n] = __builtin_amdgcn_mfma_f32_16x16x32_bf16(ah[m], bh[n], acc[m][n], 0, 0, 0);
        }
    }
    __syncthreads();
  }

  const int crow = (lane >> 4) * 4;
  const int ccol = lane & 15;
#pragma unroll
  for (int m = 0; m < 4; ++m)
#pragma unroll
    for (int j = 0; j < 4; ++j) {
      float* cp = C + (size_t)(r0 + wr * 64 + m * 16 + crow + j) * ldc + c0 + wc * 64 + ccol;
#pragma unroll
      for (int n = 0; n < 4; ++n) cp[n * 16] = acc[m][n][j];
    }
}

// ---------------------------------------------------------------------------
// f32 -> (bf16 hi, bf16 lo) split casts.
// ---------------------------------------------------------------------------
__device__ __forceinline__ void split8_store(const float* f, ushort* hi, ushort* lo, size_t e)
{
  ushort h[8], l[8];
#pragma unroll
  for (int j = 0; j < 8; ++j) {
    h[j] = f2b(f[j]);
    l[j] = f2b(f[j] - b2f(h[j]));
  }
  uint4 ph, pl;
  ph.x = (uint)h[0] | ((uint)h[1] << 16); ph.y = (uint)h[2] | ((uint)h[3] << 16);
  ph.z = (uint)h[4] | ((uint)h[5] << 16); ph.w = (uint)h[6] | ((uint)h[7] << 16);
  pl.x = (uint)l[0] | ((uint)l[1] << 16); pl.y = (uint)l[2] | ((uint)l[3] << 16);
  pl.z = (uint)l[4] | ((uint)l[5] << 16); pl.w = (uint)l[6] | ((uint)l[7] << 16);
  *(uint4*)(hi + e) = ph;
  *(uint4*)(lo + e) = pl;
}

__global__ void cast_pair_kernel(const float* __restrict__ src,
                                 ushort* __restrict__ hi, ushort* __restrict__ lo)
{
  int cid = blockIdx.x * blockDim.x + threadIdx.x;
  size_t e = (size_t)cid * 8;
  float f[8];
  *(float4*)(f)     = *(const float4*)(src + e);
  *(float4*)(f + 4) = *(const float4*)(src + e + 4);
  split8_store(f, hi, lo, e);
}

__global__ void cast_qkv_kernel(const float* __restrict__ wq, const float* __restrict__ wk,
                                const float* __restrict__ wv,
                                ushort* __restrict__ hi, ushort* __restrict__ lo)
{
  int cid = blockIdx.x * blockDim.x + threadIdx.x;
  size_t e = (size_t)cid * 8;
  const float* src; size_t off;
  if (e < 1179648)      { src = wq; off = e; }
  else if (e < 2359296) { src = wk; off = e - 1179648; }
  else                  { src = wv; off = e - 2359296; }
  float f[8];
  *(float4*)(f)     = *(const float4*)(src + off);
  *(float4*)(f + 4) = *(const float4*)(src + off + 4);
  split8_store(f, hi, lo, e);
}

// ---------------------------------------------------------------------------
// Causal depthwise conv (K=4) + SiLU + FUSED L2-norm (q,k heads).
// A 64-lane wave covers exactly one 64-aligned c-chunk of one (b,t) row;
// for c<1536 that chunk IS one head's 64 dims -> wave shuffle reduce gives
// the L2 norm in-register (replaces the separate l2norm kernels).
// Writes q/k/v transposed to (B,H,T,D).
// ---------------------------------------------------------------------------
__global__ void conv_silu_kernel(
    const float* __restrict__ pre,
    const float* __restrict__ qw, const float* __restrict__ kw, const float* __restrict__ vw,
    float* __restrict__ qc, float* __restrict__ kc, float* __restrict__ vc)
{
  int idx = blockIdx.x * blockDim.x + threadIdx.x;
  int c  = idx % CQKV;
  int bt = idx / CQKV;
  int t  = bt % TT;
  int b  = bt / TT;

  const float* wp;
  if (c < TQK)          wp = qw + (size_t)c * 4;
  else if (c < 2 * TQK) wp = kw + (size_t)(c - TQK) * 4;
  else                  wp = vw + (size_t)(c - 2 * TQK) * 4;

  float s = 0.f;
#pragma unroll
  for (int j = 0; j < 4; ++j) {
    int ts = t - 3 + j;
    if (ts >= 0) s = fmaf(pre[(size_t)(b * TT + ts) * CQKV + c], wp[j], s);
  }
  s = siluf(s);

  if (c < 2 * TQK) {           // q or k: fused L2 norm over the 64-lane head
    float ss = s * s;
#pragma unroll
    for (int m = 32; m >= 1; m >>= 1) ss += __shfl_xor(ss, m, 64);
    s = s / fmaxf(sqrtf(ss), EPSF);
  }

  if (c < TQK) {
    int h = c >> 6, d = c & 63;
    qc[((size_t)(b * HH + h) * TT + t) * 64 + d] = s;
  } else if (c < 2 * TQK) {
    int c2 = c - TQK; int h = c2 >> 6, d = c2 & 63;
    kc[((size_t)(b * HH + h) * TT + t) * 64 + d] = s;
  } else {
    int c2 = c - 2 * TQK; int h = c2 >> 7, d = c2 & 127;
    vc[((size_t)(b * HH + h) * TT + t) * 128 + d] = s;
  }
}

// ---------------------------------------------------------------------------
// Gating: one block per row m; 4 waves x 6 outputs. Writes INTERLEAVED
// (alpha,beta) pairs: abi[((b*HH+h)*TT + t)*2 + {0,1}].
// ---------------------------------------------------------------------------
__global__ __launch_bounds__(256) void gate_kernel(
    const float* __restrict__ x, const float* __restrict__ w_a, const float* __restrict__ w_b,
    const float* __restrict__ A_log, const float* __restrict__ dt_bias,
    float* __restrict__ abi)
{
  const int m    = blockIdx.x;
  const int w    = threadIdx.x >> 6;
  const int lane = threadIdx.x & 63;
  const float* xr = x + (size_t)m * DD;
  float xv[24];
#pragma unroll
  for (int i = 0; i < 24; ++i) xv[i] = xr[lane + i * 64];
  const int b = m / TT, t = m % TT;
#pragma unroll
  for (int j = 0; j < 6; ++j) {
    int o = w * 6 + j;
    bool isA = o < HH;
    int h = isA ? o : o - HH;
    const float* wr = (isA ? w_a : w_b) + (size_t)h * DD;
    float s = 0.f;
#pragma unroll
    for (int i = 0; i < 24; ++i) s = fmaf(xv[i], wr[lane + i * 64], s);
#pragma unroll
    for (int mm = 32; mm >= 1; mm >>= 1) s += __shfl_xor(s, mm, 64);
    if (lane == 0) {
      size_t idx = ((size_t)(b * HH + h) * TT + t) * 2;
      if (isA) {
        float a  = s + dt_bias[h];
        float sp = (a > 20.f) ? a : log1pf(expf(a));
        abi[idx] = expf(-expf(A_log[h]) * sp);
      } else {
        abi[idx + 1] = 2.f / (1.f + expf(-s));
      }
    }
  }
}

// ---------------------------------------------------------------------------
// Gated delta scan v7 = R10 + STATIC double buffer: separate __shared__
// objects with literal indices so alias analysis can prove ds_reads don't
// touch the buffer being filled by global_load_lds (R10 theory: runtime
// `cur` forced compiler vmcnt(0) before LDS reads -> per-step store-drain
// ~300cy). Counted waits: vmcnt(19) after first double-stage, vmcnt(51)
// (= 32 o-stores + 19 next-stage loads newer than target buffer's loads)
// in steady state -- stores are never drained. Register depth-1 prefetch
// inside the 32-step unrolled tile kept from R10.
// 768 blocks = 32 vgroups x 24 bh, one wave each; blk = vg*24 + bh keeps all
// same-bh blocks on XCD bh%8 (L2 dedupe of broadcast k/q: FETCH 12.4 MB).
// ---------------------------------------------------------------------------
__global__ __launch_bounds__(64) void scan_kernel(
    const float* __restrict__ qc, const float* __restrict__ kc, const float* __restrict__ vc,
    const float* __restrict__ abi, float* __restrict__ o)
{
  __shared__ float k0[TSC * 64], q0[TSC * 64], v0[TSC * 4], ab0[TSC * 2];
  __shared__ float k1[TSC * 64], q1[TSC * 64], v1[TSC * 4], ab1[TSC * 2];

  const int blk  = blockIdx.x;
  const int bh   = blk % 24;          // XCD affinity: bh%8
  const int vg   = blk / 24;          // 0..31
  const int b    = bh / HH, h = bh % HH;
  const int lane = threadIdx.x;       // 0..63
  const int cp   = lane >> 4;         // 0..3
  const int s    = lane & 15;         // 0..15, owns d = s*4..s*4+3

  const float* kg = kc + (size_t)bh * TT * 64;
  const float* qg = qc + (size_t)bh * TT * 64;

  // per-lane gather sources
  const float* vsrc  = vc + (size_t)bh * TT * 128 + (size_t)(lane >> 2) * 128 + vg * 4 + (lane & 3);
  const float* absrc = abi + (size_t)bh * TT * 2 + lane;

  float* op = o + ((size_t)b * TT * HH + h) * 128 + vg * 4 + cp;

#define STAGE(KL, QL, VL, ABL, T0) do { \
    _Pragma("unroll") \
    for (int j = 0; j < 8; ++j) { \
      gload16(kg + (size_t)((T0) + 4 * j) * 64 + lane * 4, &KL[j * 256]); \
      gload16(qg + (size_t)((T0) + 4 * j) * 64 + lane * 4, &QL[j * 256]); \
    } \
    gload4(vsrc + (size_t)(T0) * 128,        &VL[0]);  \
    gload4(vsrc + (size_t)((T0) + 16) * 128, &VL[64]); \
    gload4(absrc + (T0) * 2, &ABL[0]); \
  } while (0)

  float S[4];
#pragma unroll
  for (int i = 0; i < 4; ++i) S[i] = 0.f;

#define COMPUTE(KL, QL, VL, ABL) do { \
    float4 kk = *(const float4*)(&KL[s * 4]); \
    float4 qq = *(const float4*)(&QL[s * 4]); \
    float  vt = VL[cp]; \
    float2 ab = *(const float2*)(&ABL[0]); \
    _Pragma("unroll") \
    for (int i = 0; i < TSC; ++i) { \
      float4 kkn = kk, qqn = qq; float vtn = vt; float2 abn = ab; \
      if (i + 1 < TSC) { \
        kkn = *(const float4*)(&KL[(i + 1) * 64 + s * 4]); \
        qqn = *(const float4*)(&QL[(i + 1) * 64 + s * 4]); \
        vtn = VL[(i + 1) * 4 + cp]; \
        abn = *(const float2*)(&ABL[2 * (i + 1)]); \
      } \
      const float al = ab.x, be = ab.y; \
      float pa = fmaf(kk.y, S[1], kk.x * S[0]); \
      float pb = fmaf(kk.w, S[3], kk.z * S[2]); \
      float sa = fmaf(qq.y, S[1], qq.x * S[0]); \
      float sb = fmaf(qq.w, S[3], qq.z * S[2]); \
      float ta = fmaf(qq.y, kk.y, qq.x * kk.x); \
      float tb = fmaf(qq.w, kk.w, qq.z * kk.z); \
      float part = red16_dpp(pa + pb); \
      float qs   = red16_dpp(sa + sb); \
      float qk   = red16_dpp(ta + tb); \
      const float c = fmaf(-al * be, part, vt); \
      S[0] = fmaf(al, S[0], c * kk.x); \
      S[1] = fmaf(al, S[1], c * kk.y); \
      S[2] = fmaf(al, S[2], c * kk.z); \
      S[3] = fmaf(al, S[3], c * kk.w); \
      if (s == 0) *op = fmaf(al, qs, c * qk); \
      op += HH * 128; \
      kk = kkn; qq = qqn; vt = vtn; ab = abn; \
    } \
  } while (0)

  // peel: fill both buffers, compute tile 0
  STAGE(k0, q0, v0, ab0, 0);
  STAGE(k1, q1, v1, ab1, TSC);
  asm volatile("s_waitcnt vmcnt(19)" ::: "memory");   // buf0 ready (19 newer = buf1 loads)
  __builtin_amdgcn_sched_barrier(0);
  COMPUTE(k0, q0, v0, ab0);                           // tile 0 (+32 stores)

  for (int t0 = 2 * TSC; t0 < TT; t0 += 2 * TSC) {    // t0 = 64,128,...,960
    STAGE(k0, q0, v0, ab0, t0);                       // +19
    asm volatile("s_waitcnt vmcnt(51)" ::: "memory"); // buf1 ready (32 stores + 19 newer)
    __builtin_amdgcn_sched_barrier(0);
    COMPUTE(k1, q1, v1, ab1);                         // tile t0-32 (+32 stores)
    STAGE(k1, q1, v1, ab1, t0 + TSC);                 // +19
    asm volatile("s_waitcnt vmcnt(51)" ::: "memory"); // buf0 ready
    __builtin_amdgcn_sched_barrier(0);
    COMPUTE(k0, q0, v0, ab0);                         // tile t0 (+32 stores)
  }
  asm volatile("s_waitcnt vmcnt(0)" ::: "memory");    // tail: buf1 holds tile 992
  __builtin_amdgcn_sched_barrier(0);
  COMPUTE(k1, q1, v1, ab1);
#undef STAGE
#undef COMPUTE
}

// ---------------------------------------------------------------------------
// RMS norm over 128 + SiLU gate; emits split bf16 (hi+lo) for final GEMM.
// ---------------------------------------------------------------------------
__global__ void rmsgate_kernel(const float* __restrict__ o, const float* __restrict__ gpre,
                               ushort* __restrict__ goh, ushort* __restrict__ gol)
{
  int gid  = blockIdx.x * blockDim.x + threadIdx.x;
  int wid  = gid >> 6;
  int lane = threadIdx.x & 63;
  if (wid >= BB * TT * HH) return;
  int h = wid % HH;
  int m = wid / HH;
  const float* orow = o + (size_t)wid * 128;
  float2 ov = *(const float2*)(orow + lane * 2);
  float ss = ov.x * ov.x + ov.y * ov.y;
#pragma unroll
  for (int mm = 32; mm >= 1; mm >>= 1) ss += __shfl_xor(ss, mm, 64);
  float scale = rsqrtf(ss * (1.f / 128.f) + EPSF);
  const float* gr = gpre + (size_t)m * TVv + h * 128 + lane * 2;
  float o0 = ov.x * scale * siluf(gr[0]);
  float o1 = ov.y * scale * siluf(gr[1]);
  ushort h0 = f2b(o0), h1 = f2b(o1);
  ushort l0 = f2b(o0 - b2f(h0)), l1 = f2b(o1 - b2f(h1));
  size_t idx = (size_t)m * TVv + h * 128 + lane * 2;
  *(uint*)(goh + idx) = (uint)h0 | ((uint)h1 << 16);
  *(uint*)(gol + idx) = (uint)l0 | ((uint)l1 << 16);
}

// ---------------------------------------------------------------------------
extern "C" void kernel_launch(void* const* d_in, const int* in_sizes, int n_in,
                              void* d_out, int out_size, void* d_ws, size_t ws_size,
                              hipStream_t stream) {
  (void)in_sizes; (void)n_in; (void)out_size; (void)ws_size;
  const float* x       = (const float*)d_in[0];
  const float* w_q     = (const float*)d_in[1];
  const float* w_k     = (const float*)d_in[2];
  const float* w_v     = (const float*)d_in[3];
  const float* w_a     = (const float*)d_in[4];
  const float* w_b     = (const float*)d_in[5];
  const float* w_g     = (const float*)d_in[6];
  const float* w_out   = (const float*)d_in[7];
  const float* A_log   = (const float*)d_in[8];
  const float* dt_bias = (const float*)d_in[9];
  const float* qcw     = (const float*)d_in[10];
  const float* kcw     = (const float*)d_in[11];
  const float* vcw     = (const float*)d_in[12];

  // Workspace (63.11 MB, same proven footprint).
  float* ws      = (float*)d_ws;
  float* qkv_pre = ws;
  float* g_pre   = ws + 6291456;
  float* Cu      = ws + 9437184;
  float* abi     = ws + 15728640;   // 49152 floats = 24576 (alpha,beta) pairs

  ushort* xh    = (ushort*)Cu;
  ushort* xl    = (ushort*)(Cu + 1572864);
  ushort* wcath = (ushort*)g_pre;
  ushort* wcatl = (ushort*)(Cu + 3145728);
  ushort* wgh   = (ushort*)(Cu + 3145728);
  ushort* wgl   = (ushort*)(Cu + 4325376);

  float* qc = Cu;
  float* kc = Cu + 1572864;
  float* vc = Cu + 3145728;

  ushort* wouth = (ushort*)Cu;
  ushort* woutl = (ushort*)(Cu + 1179648);

  float*  o   = qkv_pre;
  ushort* goh = (ushort*)(qkv_pre + 3145728);
  ushort* gol = (ushort*)(qkv_pre + 4718592);

  const int M = BB * TT;  // 2048
  dim3 blk(256);

  // 1) split-casts: x, concatenated q|k|v weights
  cast_pair_kernel<<<1536, blk, 0, stream>>>(x, xh, xl);
  cast_qkv_kernel<<<2304, blk, 0, stream>>>(w_q, w_k, w_v, wcath, wcatl);

  // 2) fused qkv projection (N=3072)
  gemm_bf16s<<<dim3(CQKV / 128, M / 128), blk, 0, stream>>>(xh, xl, wcath, wcatl, qkv_pre, M, CQKV, DD, CQKV);

  // 3) g projection
  cast_pair_kernel<<<1152, blk, 0, stream>>>(w_g, wgh, wgl);
  gemm_bf16s<<<dim3(TVv / 128, M / 128), blk, 0, stream>>>(xh, xl, wgh, wgl, g_pre, M, TVv, DD, TVv);

  // 4) gating coefficients -> interleaved (alpha,beta)
  gate_kernel<<<M, blk, 0, stream>>>(x, w_a, w_b, A_log, dt_bias, abi);

  // 5) causal depthwise conv + SiLU + fused L2 norm
  conv_silu_kernel<<<24576, blk, 0, stream>>>(qkv_pre, qcw, kcw, vcw, qc, kc, vc);

  // 6) scan v7: static double buffer, counted vmcnt
  scan_kernel<<<768, dim3(64), 0, stream>>>(qc, kc, vc, abi, o);

  // 7) split-cast w_out
  cast_pair_kernel<<<1152, blk, 0, stream>>>(w_out, wouth, woutl);

  // 8) RMS norm + SiLU gate -> split bf16
  rmsgate_kernel<<<6144, blk, 0, stream>>>(o, g_pre, goh, gol);

  // 9) output projection
  gemm_bf16s<<<dim3(TVv / 128, M / 128), blk, 0, stream>>>(goh, gol, wouth, woutl, (float*)d_out, M, TVv, DD, TVv);
}

// Round 12
// 303.372 us; speedup vs baseline: 1.4629x; 1.2512x over previous
//
#include <hip/hip_runtime.h>
#include <math.h>

#define BB 2
#define TT 1024
#define DD 1536
#define HH 12
#define TQK 768
#define TVv 1536
#define CQKV 3072
#define NQKVG 4608   // qkv (3072) + g (1536) fused projection width
#define EPSF 1e-6f
#define TSC 32       // scan time-tile (per LDS buffer)

typedef __attribute__((ext_vector_type(8))) _Float16 half8v;
typedef __attribute__((ext_vector_type(4))) float f32x4;

__device__ __forceinline__ float siluf(float x) { return x / (1.f + expf(-x)); }

__device__ __forceinline__ uint pk2h(float a, float b) {
  union { _Float16 h[2]; uint u; } p;
  p.h[0] = (_Float16)a; p.h[1] = (_Float16)b;
  return p.u;
}

// async global->LDS. dest = wave-uniform base + lane*size; src is PER-LANE.
__device__ __forceinline__ void gload16(const void* g, void* l) {
  __builtin_amdgcn_global_load_lds(
      (const __attribute__((address_space(1))) void*)g,
      (__attribute__((address_space(3))) void*)l, 16, 0, 0);
}
__device__ __forceinline__ void gload4(const void* g, void* l) {
  __builtin_amdgcn_global_load_lds(
      (const __attribute__((address_space(1))) void*)g,
      (__attribute__((address_space(3))) void*)l, 4, 0, 0);
}

// DPP add: x += lane-permuted x. Pure VALU (no DS pipe).
template <int CTRL>
__device__ __forceinline__ float dpp_xadd(float x) {
  union { float f; int i; } a, b;
  a.f = x;
  b.i = __builtin_amdgcn_update_dpp(0, a.i, CTRL, 0xF, 0xF, true);
  return x + b.f;
}
__device__ __forceinline__ float red16_dpp(float x) {
  x = dpp_xadd<0xB1>(x);   // xor1
  x = dpp_xadd<0x4E>(x);   // xor2
  x = dpp_xadd<0x141>(x);  // row_half_mirror
  x = dpp_xadd<0x140>(x);  // row_mirror
  return x;
}

// ---------------------------------------------------------------------------
// fp16 MFMA GEMM: C = X(MxK,f16) @ W(NxK,f16)^T -> f32.
// 128x128 tile, BK=64, 4 waves (2x2), 4x4 frags of mfma_f32_16x16x32_f16.
// global_load_lds staging with XOR-swizzled source + swizzled ds_read
// (proven structure from split-bf16 version; LDS now 32KB -> 4+ blocks/CU).
// Output split: block-col c0 < nsplit -> C1 (ldc1), else C2 at c0-nsplit
// (ldc2). nsplit is a multiple of 128 so blocks never straddle.
// ---------------------------------------------------------------------------
__global__ __launch_bounds__(256) void gemm_f16(
    const ushort* __restrict__ X, const ushort* __restrict__ W,
    float* __restrict__ C1, float* __restrict__ C2,
    int M, int N, int K, int ldc1, int ldc2, int nsplit)
{
  __shared__ ushort Ah[128 * 64];
  __shared__ ushort Bh[128 * 64];
  const int tid  = threadIdx.x;
  const int lane = tid & 63;
  const int w    = tid >> 6;
  const int wr   = w >> 1, wc = w & 1;
  const int r0   = blockIdx.y * 128, c0 = blockIdx.x * 128;

  const int dr   = lane >> 3;
  const int slot = (lane & 7) ^ dr;

  f32x4 acc[4][4];
#pragma unroll
  for (int m = 0; m < 4; ++m)
#pragma unroll
    for (int n = 0; n < 4; ++n)
#pragma unroll
      for (int j = 0; j < 4; ++j) acc[m][n][j] = 0.f;

  for (int k0 = 0; k0 < K; k0 += 64) {
#pragma unroll
    for (int j = 0; j < 4; ++j) {
      const int row  = (w * 4 + j) * 8 + dr;
      const size_t xo = (size_t)(r0 + row) * K + k0 + slot * 8;
      const size_t wo = (size_t)(c0 + row) * K + k0 + slot * 8;
      const int ldso = (w * 4 + j) * 512;
      gload16(X + xo, Ah + ldso);
      gload16(W + wo, Bh + ldso);
    }
    __syncthreads();
#pragma unroll
    for (int kk = 0; kk < 2; ++kk) {
      const int kc8 = kk * 4 + (lane >> 4);
      const int sw  = (kc8 ^ (lane & 7)) << 3;
      half8v a[4], b[4];
#pragma unroll
      for (int m = 0; m < 4; ++m)
        a[m] = *(const half8v*)(Ah + (wr * 64 + m * 16 + (lane & 15)) * 64 + sw);
#pragma unroll
      for (int n = 0; n < 4; ++n)
        b[n] = *(const half8v*)(Bh + (wc * 64 + n * 16 + (lane & 15)) * 64 + sw);
#pragma unroll
      for (int m = 0; m < 4; ++m)
#pragma unroll
        for (int n = 0; n < 4; ++n)
          acc[m][n] = __builtin_amdgcn_mfma_f32_16x16x32_f16(a[m], b[n], acc[m][n], 0, 0, 0);
    }
    __syncthreads();
  }

  float* Cp; int ldc, cc0;
  if (c0 < nsplit) { Cp = C1; ldc = ldc1; cc0 = c0; }
  else             { Cp = C2; ldc = ldc2; cc0 = c0 - nsplit; }

  const int crow = (lane >> 4) * 4;
  const int ccol = lane & 15;
#pragma unroll
  for (int m = 0; m < 4; ++m)
#pragma unroll
    for (int j = 0; j < 4; ++j) {
      float* cp = Cp + (size_t)(r0 + wr * 64 + m * 16 + crow + j) * ldc + cc0 + wc * 64 + ccol;
#pragma unroll
      for (int n = 0; n < 4; ++n) cp[n * 16] = acc[m][n][j];
    }
}

// ---------------------------------------------------------------------------
// f32 -> fp16 casts (8 elems/thread, exact grids).
// ---------------------------------------------------------------------------
__device__ __forceinline__ void cast8_store(const float* f, ushort* dst, size_t e)
{
  uint4 pk;
  pk.x = pk2h(f[0], f[1]); pk.y = pk2h(f[2], f[3]);
  pk.z = pk2h(f[4], f[5]); pk.w = pk2h(f[6], f[7]);
  *(uint4*)(dst + e) = pk;
}

__global__ void cast_f16_kernel(const float* __restrict__ src, ushort* __restrict__ dst)
{
  int cid = blockIdx.x * blockDim.x + threadIdx.x;
  size_t e = (size_t)cid * 8;
  float f[8];
  *(float4*)(f)     = *(const float4*)(src + e);
  *(float4*)(f + 4) = *(const float4*)(src + e + 4);
  cast8_store(f, dst, e);
}

// Concatenated q|k|v|g weight cast into (4608,1536) fp16.
__global__ void cast_w4_kernel(const float* __restrict__ wq, const float* __restrict__ wk,
                               const float* __restrict__ wv, const float* __restrict__ wg,
                               ushort* __restrict__ dst)
{
  int cid = blockIdx.x * blockDim.x + threadIdx.x;
  size_t e = (size_t)cid * 8;
  const float* src; size_t off;
  if (e < 1179648)      { src = wq; off = e; }
  else if (e < 2359296) { src = wk; off = e - 1179648; }
  else if (e < 4718592) { src = wv; off = e - 2359296; }
  else                  { src = wg; off = e - 4718592; }
  float f[8];
  *(float4*)(f)     = *(const float4*)(src + off);
  *(float4*)(f + 4) = *(const float4*)(src + off + 4);
  cast8_store(f, dst, e);
}

// ---------------------------------------------------------------------------
// Causal depthwise conv (K=4) + SiLU + fused L2-norm (q,k heads).
// Wave = one 64-aligned c-chunk of one (b,t) row; for q/k that chunk is one
// head -> in-register shuffle reduce for the norm. Writes (B,H,T,D).
// ---------------------------------------------------------------------------
__global__ void conv_silu_kernel(
    const float* __restrict__ pre,
    const float* __restrict__ qw, const float* __restrict__ kw, const float* __restrict__ vw,
    float* __restrict__ qc, float* __restrict__ kc, float* __restrict__ vc)
{
  int idx = blockIdx.x * blockDim.x + threadIdx.x;
  int c  = idx % CQKV;
  int bt = idx / CQKV;
  int t  = bt % TT;
  int b  = bt / TT;

  const float* wp;
  if (c < TQK)          wp = qw + (size_t)c * 4;
  else if (c < 2 * TQK) wp = kw + (size_t)(c - TQK) * 4;
  else                  wp = vw + (size_t)(c - 2 * TQK) * 4;

  float s = 0.f;
#pragma unroll
  for (int j = 0; j < 4; ++j) {
    int ts = t - 3 + j;
    if (ts >= 0) s = fmaf(pre[(size_t)(b * TT + ts) * CQKV + c], wp[j], s);
  }
  s = siluf(s);

  if (c < 2 * TQK) {           // q or k: fused L2 norm over the 64-lane head
    float ss = s * s;
#pragma unroll
    for (int m = 32; m >= 1; m >>= 1) ss += __shfl_xor(ss, m, 64);
    s = s / fmaxf(sqrtf(ss), EPSF);
  }

  if (c < TQK) {
    int h = c >> 6, d = c & 63;
    qc[((size_t)(b * HH + h) * TT + t) * 64 + d] = s;
  } else if (c < 2 * TQK) {
    int c2 = c - TQK; int h = c2 >> 6, d = c2 & 63;
    kc[((size_t)(b * HH + h) * TT + t) * 64 + d] = s;
  } else {
    int c2 = c - 2 * TQK; int h = c2 >> 7, d = c2 & 127;
    vc[((size_t)(b * HH + h) * TT + t) * 128 + d] = s;
  }
}

// ---------------------------------------------------------------------------
// Gating: one block per row m; 4 waves x 6 outputs. Writes INTERLEAVED
// (alpha,beta) pairs: abi[((b*HH+h)*TT + t)*2 + {0,1}].
// ---------------------------------------------------------------------------
__global__ __launch_bounds__(256) void gate_kernel(
    const float* __restrict__ x, const float* __restrict__ w_a, const float* __restrict__ w_b,
    const float* __restrict__ A_log, const float* __restrict__ dt_bias,
    float* __restrict__ abi)
{
  const int m    = blockIdx.x;
  const int w    = threadIdx.x >> 6;
  const int lane = threadIdx.x & 63;
  const float* xr = x + (size_t)m * DD;
  float xv[24];
#pragma unroll
  for (int i = 0; i < 24; ++i) xv[i] = xr[lane + i * 64];
  const int b = m / TT, t = m % TT;
#pragma unroll
  for (int j = 0; j < 6; ++j) {
    int o = w * 6 + j;
    bool isA = o < HH;
    int h = isA ? o : o - HH;
    const float* wr = (isA ? w_a : w_b) + (size_t)h * DD;
    float s = 0.f;
#pragma unroll
    for (int i = 0; i < 24; ++i) s = fmaf(xv[i], wr[lane + i * 64], s);
#pragma unroll
    for (int mm = 32; mm >= 1; mm >>= 1) s += __shfl_xor(s, mm, 64);
    if (lane == 0) {
      size_t idx = ((size_t)(b * HH + h) * TT + t) * 2;
      if (isA) {
        float a  = s + dt_bias[h];
        float sp = (a > 20.f) ? a : log1pf(expf(a));
        abi[idx] = expf(-expf(A_log[h]) * sp);
      } else {
        abi[idx + 1] = 2.f / (1.f + expf(-s));
      }
    }
  }
}

// ---------------------------------------------------------------------------
// Gated delta scan v8 = R11 (static dbuf, counted vmcnt) with a 2-reduce
// step: o = q . S_new (algebraically == al*(q.S_old) + c*(q.k)) -- drops one
// dot + one 4-level DPP reduce per step (~26% fewer instructions; the scan
// is single-wave issue/hazard-bound). q.S_new reads S but doesn't write, so
// it stays off the next step's serial chain.
// 768 blocks = 32 vgroups x 24 bh, one wave each; blk = vg*24 + bh keeps all
// same-bh blocks on XCD bh%8 (L2 dedupe of broadcast k/q: FETCH 12.5 MB).
// ---------------------------------------------------------------------------
__global__ __launch_bounds__(64) void scan_kernel(
    const float* __restrict__ qc, const float* __restrict__ kc, const float* __restrict__ vc,
    const float* __restrict__ abi, float* __restrict__ o)
{
  __shared__ float k0[TSC * 64], q0[TSC * 64], v0[TSC * 4], ab0[TSC * 2];
  __shared__ float k1[TSC * 64], q1[TSC * 64], v1[TSC * 4], ab1[TSC * 2];

  const int blk  = blockIdx.x;
  const int bh   = blk % 24;          // XCD affinity: bh%8
  const int vg   = blk / 24;          // 0..31
  const int b    = bh / HH, h = bh % HH;
  const int lane = threadIdx.x;       // 0..63
  const int cp   = lane >> 4;         // 0..3
  const int s    = lane & 15;         // 0..15, owns d = s*4..s*4+3

  const float* kg = kc + (size_t)bh * TT * 64;
  const float* qg = qc + (size_t)bh * TT * 64;

  const float* vsrc  = vc + (size_t)bh * TT * 128 + (size_t)(lane >> 2) * 128 + vg * 4 + (lane & 3);
  const float* absrc = abi + (size_t)bh * TT * 2 + lane;

  float* op = o + ((size_t)b * TT * HH + h) * 128 + vg * 4 + cp;

#define STAGE(KL, QL, VL, ABL, T0) do { \
    _Pragma("unroll") \
    for (int j = 0; j < 8; ++j) { \
      gload16(kg + (size_t)((T0) + 4 * j) * 64 + lane * 4, &KL[j * 256]); \
      gload16(qg + (size_t)((T0) + 4 * j) * 64 + lane * 4, &QL[j * 256]); \
    } \
    gload4(vsrc + (size_t)(T0) * 128,        &VL[0]);  \
    gload4(vsrc + (size_t)((T0) + 16) * 128, &VL[64]); \
    gload4(absrc + (T0) * 2, &ABL[0]); \
  } while (0)

  float S[4];
#pragma unroll
  for (int i = 0; i < 4; ++i) S[i] = 0.f;

#define COMPUTE(KL, QL, VL, ABL) do { \
    float4 kk = *(const float4*)(&KL[s * 4]); \
    float4 qq = *(const float4*)(&QL[s * 4]); \
    float  vt = VL[cp]; \
    float2 ab = *(const float2*)(&ABL[0]); \
    _Pragma("unroll") \
    for (int i = 0; i < TSC; ++i) { \
      float4 kkn = kk, qqn = qq; float vtn = vt; float2 abn = ab; \
      if (i + 1 < TSC) { \
        kkn = *(const float4*)(&KL[(i + 1) * 64 + s * 4]); \
        qqn = *(const float4*)(&QL[(i + 1) * 64 + s * 4]); \
        vtn = VL[(i + 1) * 4 + cp]; \
        abn = *(const float2*)(&ABL[2 * (i + 1)]); \
      } \
      const float al = ab.x, be = ab.y; \
      float pa = fmaf(kk.y, S[1], kk.x * S[0]); \
      float pb = fmaf(kk.w, S[3], kk.z * S[2]); \
      float part = red16_dpp(pa + pb); \
      const float c = fmaf(-al * be, part, vt); \
      S[0] = fmaf(al, S[0], c * kk.x); \
      S[1] = fmaf(al, S[1], c * kk.y); \
      S[2] = fmaf(al, S[2], c * kk.z); \
      S[3] = fmaf(al, S[3], c * kk.w); \
      float sa = fmaf(qq.y, S[1], qq.x * S[0]); \
      float sb = fmaf(qq.w, S[3], qq.z * S[2]); \
      float qs = red16_dpp(sa + sb); \
      if (s == 0) *op = qs; \
      op += HH * 128; \
      kk = kkn; qq = qqn; vt = vtn; ab = abn; \
    } \
  } while (0)

  // peel: fill both buffers, compute tile 0
  STAGE(k0, q0, v0, ab0, 0);
  STAGE(k1, q1, v1, ab1, TSC);
  asm volatile("s_waitcnt vmcnt(19)" ::: "memory");   // buf0 ready (19 newer = buf1 loads)
  __builtin_amdgcn_sched_barrier(0);
  COMPUTE(k0, q0, v0, ab0);                           // tile 0 (+32 stores)

  for (int t0 = 2 * TSC; t0 < TT; t0 += 2 * TSC) {    // t0 = 64,128,...,960
    STAGE(k0, q0, v0, ab0, t0);                       // +19
    asm volatile("s_waitcnt vmcnt(51)" ::: "memory"); // buf1 ready (32 stores + 19 newer)
    __builtin_amdgcn_sched_barrier(0);
    COMPUTE(k1, q1, v1, ab1);                         // tile t0-32 (+32 stores)
    STAGE(k1, q1, v1, ab1, t0 + TSC);                 // +19
    asm volatile("s_waitcnt vmcnt(51)" ::: "memory"); // buf0 ready
    __builtin_amdgcn_sched_barrier(0);
    COMPUTE(k0, q0, v0, ab0);                         // tile t0 (+32 stores)
  }
  asm volatile("s_waitcnt vmcnt(0)" ::: "memory");    // tail: buf1 holds tile 992
  __builtin_amdgcn_sched_barrier(0);
  COMPUTE(k1, q1, v1, ab1);
#undef STAGE
#undef COMPUTE
}

// ---------------------------------------------------------------------------
// RMS norm over 128 + SiLU gate; emits fp16 for the final GEMM.
// ---------------------------------------------------------------------------
__global__ void rmsgate_kernel(const float* __restrict__ o, const float* __restrict__ gpre,
                               ushort* __restrict__ gof)
{
  int gid  = blockIdx.x * blockDim.x + threadIdx.x;
  int wid  = gid >> 6;
  int lane = threadIdx.x & 63;
  if (wid >= BB * TT * HH) return;
  int h = wid % HH;
  int m = wid / HH;
  const float* orow = o + (size_t)wid * 128;
  float2 ov = *(const float2*)(orow + lane * 2);
  float ss = ov.x * ov.x + ov.y * ov.y;
#pragma unroll
  for (int mm = 32; mm >= 1; mm >>= 1) ss += __shfl_xor(ss, mm, 64);
  float scale = rsqrtf(ss * (1.f / 128.f) + EPSF);
  const float* gr = gpre + (size_t)m * TVv + h * 128 + lane * 2;
  float o0 = ov.x * scale * siluf(gr[0]);
  float o1 = ov.y * scale * siluf(gr[1]);
  *(uint*)(gof + (size_t)m * TVv + h * 128 + lane * 2) = pk2h(o0, o1);
}

// ---------------------------------------------------------------------------
extern "C" void kernel_launch(void* const* d_in, const int* in_sizes, int n_in,
                              void* d_out, int out_size, void* d_ws, size_t ws_size,
                              hipStream_t stream) {
  (void)in_sizes; (void)n_in; (void)out_size; (void)ws_size;
  const float* x       = (const float*)d_in[0];
  const float* w_q     = (const float*)d_in[1];
  const float* w_k     = (const float*)d_in[2];
  const float* w_v     = (const float*)d_in[3];
  const float* w_a     = (const float*)d_in[4];
  const float* w_b     = (const float*)d_in[5];
  const float* w_g     = (const float*)d_in[6];
  const float* w_out   = (const float*)d_in[7];
  const float* A_log   = (const float*)d_in[8];
  const float* dt_bias = (const float*)d_in[9];
  const float* qcw     = (const float*)d_in[10];
  const float* kcw     = (const float*)d_in[11];
  const float* vcw     = (const float*)d_in[12];

  // Workspace (63.11 MB, same proven footprint). fp16 halves the low-prec
  // buffers so phase-1 (xf + wcat4) now fits entirely inside Cu:
  //   Cu phase1: xf [0,1572864)f, wcat [1572864,5111808)f  (< 6291456) ✓
  //   Cu phase2: qc/kc/vc ; Cu phase3: woutf
  float* ws      = (float*)d_ws;
  float* qkv_pre = ws;
  float* g_pre   = ws + 6291456;
  float* Cu      = ws + 9437184;
  float* abi     = ws + 15728640;   // 49152 floats = 24576 (alpha,beta) pairs

  ushort* xf    = (ushort*)Cu;                 // 3,145,728 ushorts
  ushort* wcat  = (ushort*)(Cu + 1572864);     // 7,077,888 ushorts (q|k|v|g)

  float* qc = Cu;
  float* kc = Cu + 1572864;
  float* vc = Cu + 3145728;

  ushort* woutf = (ushort*)Cu;                 // 2,359,296 ushorts (phase 3)

  float*  o   = qkv_pre;
  ushort* gof = (ushort*)(qkv_pre + 3145728);  // 3,145,728 ushorts

  const int M = BB * TT;  // 2048
  dim3 blk(256);

  // 1) fp16 casts: x, concatenated q|k|v|g weights
  cast_f16_kernel<<<1536, blk, 0, stream>>>(x, xf);
  cast_w4_kernel<<<3456, blk, 0, stream>>>(w_q, w_k, w_v, w_g, wcat);

  // 2) fused qkv+g projection (N=4608, split epilogue)
  gemm_f16<<<dim3(NQKVG / 128, M / 128), blk, 0, stream>>>(
      xf, wcat, qkv_pre, g_pre, M, NQKVG, DD, CQKV, TVv, CQKV);

  // 3) gating coefficients -> interleaved (alpha,beta)
  gate_kernel<<<M, blk, 0, stream>>>(x, w_a, w_b, A_log, dt_bias, abi);

  // 4) causal depthwise conv + SiLU + fused L2 norm
  conv_silu_kernel<<<24576, blk, 0, stream>>>(qkv_pre, qcw, kcw, vcw, qc, kc, vc);

  // 5) scan v8: 2-reduce step
  scan_kernel<<<768, dim3(64), 0, stream>>>(qc, kc, vc, abi, o);

  // 6) cast w_out -> fp16 (into freed qc space)
  cast_f16_kernel<<<1152, blk, 0, stream>>>(w_out, woutf);

  // 7) RMS norm + SiLU gate -> fp16
  rmsgate_kernel<<<6144, blk, 0, stream>>>(o, g_pre, gof);

  // 8) output projection
  gemm_f16<<<dim3(TVv / 128, M / 128), blk, 0, stream>>>(
      gof, woutf, (float*)d_out, (float*)d_out, M, TVv, DD, TVv, TVv, TVv);
}